// Round 7
// baseline (578.565 us; speedup 1.0000x reference)
//
#include <hip/hip_runtime.h>
#include <stdint.h>

// ---------------------------------------------------------------------------
// Qwen attention block: x@Wqkv -> RMSnorm -> RoPE -> causal GQA flash attn ->
// @Wo.  B=2 T=2048 D=2048 H=16 KH=8 Hd=128.  bf16 MFMA, f32 accum.
// R7: attn LDS 64->48KB for 3 blocks/CU: V single-buffered + reg-staged
// (T14 split: global->reg issued early, ds_write after barrier), K stays
// gload_lds double-buffered; raw s_barrier + counted vmcnt (no __syncthreads
// in main loop).  GEMMs/others unchanged from R6.
// ---------------------------------------------------------------------------

#define B_ 2
#define T_ 2048
#define D_ 2048
#define H_ 16
#define KH_ 8
#define HD_ 128
#define M_ (B_*T_)          // 4096 tokens
#define NQKV_ 4096          // q(2048) | k(1024) | v(1024)
#define QK_SCALE_LOG2E 0.1275174337f

typedef unsigned short u16;
typedef unsigned int   u32;
typedef __attribute__((ext_vector_type(8)))  __bf16 bf16x8_t;
typedef __attribute__((ext_vector_type(4)))  float  f32x4_t;
typedef __attribute__((ext_vector_type(16))) float  f32x16_t;
typedef __attribute__((ext_vector_type(4)))  u32    u32x4_t;

__device__ __forceinline__ u16 f2bf(float f) {          // RNE f32 -> bf16
    u32 x = __float_as_uint(f);
    return (u16)((x + 0x7fffu + ((x >> 16) & 1u)) >> 16);
}
__device__ __forceinline__ u32 pack2(u16 a, u16 b) { return (u32)a | ((u32)b << 16); }

// async global->LDS, 16B per lane.  LDS dest is wave-uniform base; lane i's
// 16B lands at base + i*16.
__device__ __forceinline__ void gload16(const void* g, void* l) {
    __builtin_amdgcn_global_load_lds(
        (__attribute__((address_space(1))) const void*)(unsigned long long)g,
        (__attribute__((address_space(3))) void*)(u32)(unsigned long long)l,
        16, 0, 0);
}

// ---------------------------------------------------------------------------
// 1) cast x (f32) -> bf16
// ---------------------------------------------------------------------------
__global__ void cast_x_kernel(const float* __restrict__ in, u16* __restrict__ out) {
    int i = (blockIdx.x * 256 + threadIdx.x) * 4;
    float4 v = *(const float4*)(in + i);
    u32 lo = pack2(f2bf(v.x), f2bf(v.y));
    u32 hi = pack2(f2bf(v.z), f2bf(v.w));
    *(uint2*)(out + i) = make_uint2(lo, hi);
}

// ---------------------------------------------------------------------------
// 2) transpose+cast weight: in f32 [2048][ncols] -> out bf16 [ncols][2048]
// ---------------------------------------------------------------------------
__global__ void tcast_kernel(const float* __restrict__ in, u16* __restrict__ out,
                             int ncols) {
    __shared__ u16 tile[64][65];
    int k0 = blockIdx.x * 64;
    int n0 = blockIdx.y * 64;
    int tid = threadIdx.x;
#pragma unroll
    for (int i = 0; i < 8; ++i) {
        int idx = tid + i * 256;
        int r = idx >> 5, c2 = idx & 31;
        float2 v = *(const float2*)(in + (size_t)(k0 + r) * ncols + n0 + 2 * c2);
        tile[r][2 * c2]     = f2bf(v.x);
        tile[r][2 * c2 + 1] = f2bf(v.y);
    }
    __syncthreads();
#pragma unroll
    for (int i = 0; i < 8; ++i) {
        int idx = tid + i * 256;
        int rn = idx >> 5, c2 = idx & 31;
        *(u32*)(out + (size_t)(n0 + rn) * 2048 + k0 + 2 * c2) =
            pack2(tile[2 * c2][rn], tile[2 * c2 + 1][rn]);
    }
}

// ---------------------------------------------------------------------------
// 3) GEMM, 256x256 tile, BK=64, 8 waves, 8-phase counted-vmcnt pipeline
//    (unchanged from R6).
// ---------------------------------------------------------------------------
#define NKT 32              // K = 2048 / BK = 64

__global__ void __launch_bounds__(512, 2)
gemm8p_kernel(const u16* __restrict__ A, const u16* __restrict__ Bt,
              float* __restrict__ C, int N) {
    __shared__ u16 As[2][256 * 64];
    __shared__ u16 Bs[2][256 * 64];
    const int tid  = threadIdx.x;
    const int lane = tid & 63;
    const int w    = tid >> 6;
    const int wm   = w >> 2;
    const int wn   = w & 3;
    const int m0 = blockIdx.x * 256;
    const int n0 = blockIdx.y * 256;
    const int fr = lane & 15;
    const int kg = lane >> 4;

    const u16* Ag = A  + (size_t)m0 * 2048;
    const u16* Bg = Bt + (size_t)n0 * 2048;

#define STG(gbase, lbase, h, kt_)                                              \
    do {                                                                       \
        int _k0 = (kt_) * 64;                                                  \
        _Pragma("unroll")                                                      \
        for (int _i = 0; _i < 2; ++_i) {                                       \
            int _r  = _i * 64 + w * 8 + (lane >> 3);                           \
            int _sl = (lane & 7) ^ (_r & 7);                                   \
            gload16((gbase) + (size_t)((h) * 128 + _r) * 2048 + _k0 + _sl * 8, \
                    (lbase) + (h) * 8192 + (_i * 512 + w * 64) * 8);           \
        }                                                                      \
    } while (0)

    bf16x8_t afr[4][2];
    bf16x8_t bfr[2][2][2];
    f32x4_t  acc[8][4];
#pragma unroll
    for (int i = 0; i < 8; ++i)
#pragma unroll
        for (int j = 0; j < 4; ++j)
#pragma unroll
            for (int e = 0; e < 4; ++e) acc[i][j][e] = 0.0f;

#define RDA(qm)                                                                \
    _Pragma("unroll")                                                          \
    for (int _mf = 0; _mf < 4; ++_mf)                                          \
        _Pragma("unroll")                                                      \
        for (int _ks = 0; _ks < 2; ++_ks) {                                    \
            int _row  = wm * 128 + ((qm) * 4 + _mf) * 16 + fr;                 \
            int _phys = (_ks * 4 + kg) ^ (_row & 7);                           \
            afr[_mf][_ks] = *(const bf16x8_t*)(Asc + _row * 64 + _phys * 8);   \
        }
#define RDB(qn)                                                                \
    _Pragma("unroll")                                                          \
    for (int _nf = 0; _nf < 2; ++_nf)                                          \
        _Pragma("unroll")                                                      \
        for (int _ks = 0; _ks < 2; ++_ks) {                                    \
            int _row  = wn * 64 + ((qn) * 2 + _nf) * 16 + fr;                  \
            int _phys = (_ks * 4 + kg) ^ (_row & 7);                           \
            bfr[qn][_nf][_ks] = *(const bf16x8_t*)(Bsc + _row * 64 + _phys * 8);\
        }
#define MM(qm, qn)                                                             \
    _Pragma("unroll")                                                          \
    for (int _mf = 0; _mf < 4; ++_mf)                                          \
        _Pragma("unroll")                                                      \
        for (int _nf = 0; _nf < 2; ++_nf)                                      \
            _Pragma("unroll")                                                  \
            for (int _ks = 0; _ks < 2; ++_ks)                                  \
                acc[(qm) * 4 + _mf][(qn) * 2 + _nf] =                          \
                    __builtin_amdgcn_mfma_f32_16x16x32_bf16(                   \
                        afr[_mf][_ks], bfr[qn][_nf][_ks],                      \
                        acc[(qm) * 4 + _mf][(qn) * 2 + _nf], 0, 0, 0);

#define SBAR __builtin_amdgcn_sched_barrier(0)
#define PH_MID                                                                 \
    SBAR; __builtin_amdgcn_s_barrier();                                        \
    asm volatile("s_waitcnt lgkmcnt(0)" ::: "memory"); SBAR;                   \
    __builtin_amdgcn_s_setprio(1)
#define PH_END                                                                 \
    __builtin_amdgcn_s_setprio(0); SBAR;                                       \
    __builtin_amdgcn_s_barrier(); SBAR

    STG(Ag, &As[0][0], 0, 0);
    STG(Ag, &As[0][0], 1, 0);
    STG(Bg, &Bs[0][0], 0, 0);
    STG(Bg, &Bs[0][0], 1, 0);
    STG(Bg, &Bs[1][0], 0, 1);
    STG(Bg, &Bs[1][0], 1, 1);
    asm volatile("s_waitcnt vmcnt(4)" ::: "memory");
    SBAR;
    __builtin_amdgcn_s_barrier();
    SBAR;

    for (int kt = 0; kt < NKT; ++kt) {
        const int cur = kt & 1;
        const u16* Asc = &As[cur][0];
        const u16* Bsc = &Bs[cur][0];
        u16* Aso = &As[cur ^ 1][0];
        u16* Bsw = &Bs[cur][0];
        RDA(0); RDB(0);
        if (kt + 1 < NKT) STG(Ag, Aso, 0, kt + 1);
        PH_MID; MM(0, 0); PH_END;
        RDB(1);
        if (kt + 1 < NKT) STG(Ag, Aso, 1, kt + 1);
        PH_MID; MM(0, 1); PH_END;
        RDA(1);
        if (kt + 2 < NKT) STG(Bg, Bsw, 0, kt + 2);
        PH_MID; MM(1, 0); PH_END;
        if (kt + 2 < NKT) STG(Bg, Bsw, 1, kt + 2);
        SBAR; __builtin_amdgcn_s_barrier(); SBAR;
        __builtin_amdgcn_s_setprio(1);
        MM(1, 1);
        __builtin_amdgcn_s_setprio(0); SBAR;
        if (kt < NKT - 2) asm volatile("s_waitcnt vmcnt(4)" ::: "memory");
        else              asm volatile("s_waitcnt vmcnt(0)" ::: "memory");
        SBAR;
        __builtin_amdgcn_s_barrier();
        SBAR;
    }
#undef STG
#undef RDA
#undef RDB
#undef MM
#undef PH_MID
#undef PH_END

#pragma unroll
    for (int mf = 0; mf < 8; ++mf)
#pragma unroll
        for (int nf = 0; nf < 4; ++nf) {
            int colx  = n0 + wn * 64 + nf * 16 + fr;
            int rbase = m0 + wm * 128 + mf * 16 + kg * 4;
#pragma unroll
            for (int j = 0; j < 4; ++j)
                C[(size_t)(rbase + j) * N + colx] = acc[mf][nf][j];
        }
}

// ---------------------------------------------------------------------------
// 4) RMSnorm + RoPE.  One wave per (token, head-row).
// ---------------------------------------------------------------------------
__global__ void __launch_bounds__(256)
normrope_kernel(const float* __restrict__ Cqkv,
                const float* __restrict__ qw, const float* __restrict__ kw,
                const float* __restrict__ sinT, const float* __restrict__ cosT,
                u16* __restrict__ qbf, u16* __restrict__ kbf, u16* __restrict__ vbf) {
    int lane = threadIdx.x & 63;
    int w    = threadIdx.x >> 6;
    int rid  = blockIdx.x * 4 + w;
    int m   = rid >> 5;
    int sub = rid & 31;
    int b = m >> 11, t = m & (T_ - 1);

    if (sub >= 24) {                                     // v: plain cast
        int kh = sub - 24;
        float2 x = *(const float2*)(Cqkv + (size_t)m * NQKV_ + 3072 + kh * HD_ + 2 * lane);
        *(u32*)(vbf + ((size_t)(b * KH_ + kh) * T_ + t) * HD_ + 2 * lane) =
            pack2(f2bf(x.x), f2bf(x.y));
        return;
    }
    bool isq = sub < 16;
    int  hh  = isq ? sub : sub - 16;
    int  colbase = isq ? hh * HD_ : 2048 + hh * HD_;
    float2 x = *(const float2*)(Cqkv + (size_t)m * NQKV_ + colbase + 2 * lane);
    float ss = x.x * x.x + x.y * x.y;
#pragma unroll
    for (int sh = 1; sh < 64; sh <<= 1) ss += __shfl_xor(ss, sh, 64);
    float scale = rsqrtf(ss * (1.0f / 128.0f) + 1e-6f);
    const float* wp = isq ? qw : kw;
    float2 wv = *(const float2*)(wp + 2 * lane);
    float y1 = x.x * scale * wv.x;
    float y2 = x.y * scale * wv.y;
    float c = cosT[t * 64 + lane], s = sinT[t * 64 + lane];
    float oa = y1 * c - y2 * s;
    float ob = y1 * s + y2 * c;
    if (isq) { oa *= QK_SCALE_LOG2E; ob *= QK_SCALE_LOG2E; }
    u16* outp = isq ? (qbf + ((size_t)(b * H_  + hh) * T_ + t) * HD_)
                    : (kbf + ((size_t)(b * KH_ + hh) * T_ + t) * HD_);
    outp[lane]      = f2bf(oa);
    outp[64 + lane] = f2bf(ob);
}

// ---------------------------------------------------------------------------
// 5) V transpose: [BH][T][128] -> [BH][128][T]
// ---------------------------------------------------------------------------
__global__ void vtrans_kernel(const u16* __restrict__ in, u16* __restrict__ out) {
    __shared__ u16 tile[64][65];
    int t0 = blockIdx.x * 64;
    int d0 = blockIdx.y * 64;
    size_t bi = (size_t)blockIdx.z * T_ * HD_;
    size_t bo = (size_t)blockIdx.z * HD_ * T_;
    int tid = threadIdx.x;
#pragma unroll
    for (int i = 0; i < 8; ++i) {
        int idx = tid + i * 256;
        int r = idx >> 5, c2 = idx & 31;
        u32 v = *(const u32*)(in + bi + (size_t)(t0 + r) * HD_ + d0 + 2 * c2);
        tile[r][2 * c2]     = (u16)(v & 0xffffu);
        tile[r][2 * c2 + 1] = (u16)(v >> 16);
    }
    __syncthreads();
#pragma unroll
    for (int i = 0; i < 8; ++i) {
        int idx = tid + i * 256;
        int rd = idx >> 5, c2 = idx & 31;
        *(u32*)(out + bo + (size_t)(d0 + rd) * T_ + t0 + 2 * c2) =
            pack2(tile[2 * c2][rd], tile[2 * c2 + 1][rd]);
    }
}

// ---------------------------------------------------------------------------
// 6) Causal GQA flash attention, R7 structure.
//    4 waves x 32 q-rows (QBLK=128); KV tile 64.
//    K double-buffered [2][64][16 slots] via gload_lds (32KB).
//    V single LDS buffer [128][8 slots] (16KB), reg-staged: global->reg
//    issued one tile early, ds_write at tile start (T14 split).
//    48KB LDS -> 3 blocks/CU.  Raw s_barrier + counted vmcnt in main loop.
//    Math identical to R5/R6 (swapped QK^T / swapped PV, lane-local softmax).
// ---------------------------------------------------------------------------
__global__ void __launch_bounds__(256, 3)
attn_kernel(const u16* __restrict__ qg, const u16* __restrict__ kgl,
            const u16* __restrict__ vtg, u16* __restrict__ attout) {
    __shared__ u16 Kt[2][64 * 128];     // 16 KB each: rows = kv, 16 slots of 16B
    __shared__ u16 Vt[128 * 64];        // 16 KB: rows = d, 8 slots of 16B

    const int tid = threadIdx.x, lane = tid & 63, w = tid >> 6;
    const int qb = (int)gridDim.x - 1 - (int)blockIdx.x;   // big blocks first
    const int h = blockIdx.y, b = blockIdx.z;
    const int kh = h >> 1;                       // GQA rep=2
    const int q0 = qb * 128;
    const int col = lane & 31;
    const int hi  = lane >> 5;
    const int l7  = lane & 7;
    const int l15 = lane & 15;
    const int qw0 = q0 + w * 32;
    const int qlane = qw0 + col;

    const u16* qbase = qg  + ((size_t)(b * H_  + h ) * T_) * HD_;
    const u16* kbase = kgl + ((size_t)(b * KH_ + kh) * T_) * HD_;
    const u16* vbase = vtg + ((size_t)(b * KH_ + kh) * HD_) * T_;

    // Q as B-operand fragments
    bf16x8_t qf[8];
#pragma unroll
    for (int s = 0; s < 8; ++s)
        qf[s] = *(const bf16x8_t*)(qbase + (size_t)qlane * HD_ + s * 16 + hi * 8);

    // staging lane roles
    const int krl = lane >> 4, kcl = lane & 15;   // K chunk: 4 rows x 16 slots
    const int vrl = lane >> 3, vcl = lane & 7;    // V chunk: 8 rows x 8 slots

    f32x16_t o[4];
#pragma unroll
    for (int dt = 0; dt < 4; ++dt)
#pragma unroll
        for (int r = 0; r < 16; ++r) o[dt][r] = 0.0f;
    float mrow = -1e30f, lrow = 0.0f;

    const int nt = 2 * (qb + 1);                 // always even

    u32x4_t vrA[4], vrB[4];

#define SBARR __builtin_amdgcn_sched_barrier(0)

#define STAGE_K(buf, tt)                                                        \
    do {                                                                        \
        int kv0s = (tt) * 64;                                                   \
        _Pragma("unroll")                                                       \
        for (int cc = 0; cc < 4; ++cc) {                                        \
            int c = w * 4 + cc;                                                 \
            int r = c * 4 + krl;                                                \
            gload16(kbase + (size_t)(kv0s + r) * HD_ + (kcl ^ (r & 15)) * 8,    \
                    &Kt[buf][c * 512]);                                         \
        }                                                                       \
    } while (0)

#define VLOAD(VR, tt)                                                           \
    do {                                                                        \
        int kv0s = (tt) * 64;                                                   \
        _Pragma("unroll")                                                       \
        for (int cc = 0; cc < 4; ++cc) {                                        \
            int rv = (w * 4 + cc) * 8 + vrl;                                    \
            VR[cc] = *(const u32x4_t*)(vbase + (size_t)rv * T_ + kv0s +         \
                                       (vcl ^ (rv & 7)) * 8);                   \
        }                                                                       \
    } while (0)

#define DSWR(VR)                                                                \
    do {                                                                        \
        _Pragma("unroll")                                                       \
        for (int cc = 0; cc < 4; ++cc)                                          \
            *(u32x4_t*)(Vt + (w * 4 + cc) * 512 + lane * 8) = VR[cc];           \
    } while (0)

    // compute section for one tile (CUR = K buffer index)
#define COMPUTE(tt, CUR)                                                        \
    do {                                                                        \
        const int kv0 = (tt) * 64;                                              \
        const bool act = (kv0 <= qw0 + 31);                                     \
        f32x16_t s0, s1;                                                        \
        bf16x8_t pf[4];                                                         \
        if (act) {                                                              \
            _Pragma("unroll")                                                   \
            for (int r = 0; r < 16; ++r) { s0[r] = 0.0f; s1[r] = 0.0f; }        \
            __builtin_amdgcn_s_setprio(1);                                      \
            _Pragma("unroll")                                                   \
            for (int ss = 0; ss < 8; ++ss) {                                    \
                bf16x8_t kf0 = *(const bf16x8_t*)                               \
                    (&Kt[CUR][col * 128 + (((2 * ss + hi) ^ l15) * 8)]);        \
                s0 = __builtin_amdgcn_mfma_f32_32x32x16_bf16(kf0, qf[ss], s0, 0, 0, 0); \
                bf16x8_t kf1 = *(const bf16x8_t*)                               \
                    (&Kt[CUR][(32 + col) * 128 + (((2 * ss + hi) ^ l15) * 8)]); \
                s1 = __builtin_amdgcn_mfma_f32_32x32x16_bf16(kf1, qf[ss], s1, 0, 0, 0); \
            }                                                                   \
            __builtin_amdgcn_s_setprio(0);                                      \
            if (kv0 + 63 > qw0) {                                               \
                _Pragma("unroll")                                               \
                for (int r = 0; r < 16; ++r) {                                  \
                    int cr = (r & 3) + 8 * (r >> 2) + 4 * hi;                   \
                    if (kv0 + cr      > qlane) s0[r] = -1e30f;                  \
                    if (kv0 + 32 + cr > qlane) s1[r] = -1e30f;                  \
                }                                                               \
            }                                                                   \
            float tmax = s0[0];                                                 \
            _Pragma("unroll")                                                   \
            for (int r = 1; r < 16; ++r) tmax = fmaxf(tmax, s0[r]);             \
            _Pragma("unroll")                                                   \
            for (int r = 0; r < 16; ++r) tmax = fmaxf(tmax, s1[r]);             \
            tmax = fmaxf(tmax, __shfl_xor(tmax, 32, 64));                       \
            float mnew = fmaxf(mrow, tmax);                                     \
            float corr = exp2f(mrow - mnew);                                    \
            mrow = mnew;                                                        \
            float ps = 0.0f;                                                    \
            _Pragma("unroll")                                                   \
            for (int r = 0; r < 16; ++r) {                                      \
                s0[r] = exp2f(s0[r] - mrow); ps += s0[r];                       \
                s1[r] = exp2f(s1[r] - mrow); ps += s1[r];                       \
            }                                                                   \
            lrow = lrow * corr + ps;                                            \
            _Pragma("unroll")                                                   \
            for (int dt = 0; dt < 4; ++dt)                                      \
                _Pragma("unroll")                                               \
                for (int r = 0; r < 16; ++r) o[dt][r] *= corr;                  \
            u32 pd0[8], pd1[8], po0[8], po1[8];                                 \
            _Pragma("unroll")                                                   \
            for (int i = 0; i < 8; ++i) {                                       \
                pd0[i] = pack2(f2bf(s0[2 * i]), f2bf(s0[2 * i + 1]));           \
                pd1[i] = pack2(f2bf(s1[2 * i]), f2bf(s1[2 * i + 1]));           \
                po0[i] = __shfl_xor(pd0[i], 32, 64);                            \
                po1[i] = __shfl_xor(pd1[i], 32, 64);                            \
            }                                                                   \
            _Pragma("unroll")                                                   \
            for (int ks = 0; ks < 4; ++ks) {                                    \
                const u32* pd = (ks < 2) ? pd0 : pd1;                           \
                const u32* po = (ks < 2) ? po0 : po1;                           \
                int base = (ks & 1) * 4;                                        \
                union { u32 u[4]; bf16x8_t v; } f;                              \
                f.u[0] = hi ? po[base + 2] : pd[base + 0];                      \
                f.u[1] = hi ? po[base + 3] : pd[base + 1];                      \
                f.u[2] = hi ? pd[base + 2] : po[base + 0];                      \
                f.u[3] = hi ? pd[base + 3] : po[base + 1];                      \
                pf[ks] = f.v;                                                   \
            }                                                                   \
        }                                                                       \
        /* V writes visible to all before PV */                                 \
        asm volatile("s_waitcnt lgkmcnt(0)" ::: "memory");                      \
        SBARR;                                                                  \
        __builtin_amdgcn_s_barrier();                                           \
        SBARR;                                                                  \
        if (act) {                                                              \
            __builtin_amdgcn_s_setprio(1);                                      \
            _Pragma("unroll")                                                   \
            for (int dt = 0; dt < 4; ++dt) {                                    \
                int dl = dt * 32 + col;                                         \
                _Pragma("unroll")                                               \
                for (int ks = 0; ks < 4; ++ks) {                                \
                    bf16x8_t vf = *(const bf16x8_t*)                            \
                        (&Vt[dl * 64 + (((2 * ks + hi) ^ l7) * 8)]);            \
                    o[dt] = __builtin_amdgcn_mfma_f32_32x32x16_bf16(vf, pf[ks], o[dt], 0, 0, 0); \
                }                                                               \
            }                                                                   \
            __builtin_amdgcn_s_setprio(0);                                      \
        }                                                                       \
    } while (0)

    // one full tile: drain V regs, ds_write V, prefetch K/V for tt+1, compute
#define TILE(tt, CUR, VC, VN)                                                   \
    do {                                                                        \
        asm volatile("s_waitcnt vmcnt(0)" ::: "memory");                        \
        SBARR;                                                                  \
        DSWR(VC);                                                               \
        if ((tt) + 1 < nt) { STAGE_K((CUR) ^ 1, (tt) + 1); VLOAD(VN, (tt) + 1); } \
        COMPUTE(tt, CUR);                                                       \
        SBARR;                                                                  \
        if ((tt) + 1 < nt) asm volatile("s_waitcnt vmcnt(4)" ::: "memory");     \
        else               asm volatile("s_waitcnt vmcnt(0)" ::: "memory");     \
        SBARR;                                                                  \
        __builtin_amdgcn_s_barrier();                                           \
        SBARR;                                                                  \
    } while (0)

    // ---- prologue: K(0) -> LDS, V(0) -> regs ----
    STAGE_K(0, 0);
    VLOAD(vrA, 0);
    asm volatile("s_waitcnt vmcnt(4)" ::: "memory");   // K(0) done; V(0) in flight
    SBARR;
    __builtin_amdgcn_s_barrier();
    SBARR;

    for (int it = 0; it < nt; it += 2) {
        TILE(it,     0, vrA, vrB);
        TILE(it + 1, 1, vrB, vrA);
    }
#undef TILE
#undef COMPUTE
#undef DSWR
#undef VLOAD
#undef STAGE_K
#undef SBARR

    // ---- epilogue: combine l halves, O^T -> [q][d] via LDS, 16B stores ----
    float ltot = lrow + __shfl_xor(lrow, 32, 64);
    float inv  = 1.0f / ltot;
    u16* Tr = &Kt[0][0] + w * 4096;     // per-wave 32 q x 128 d region (8 KB)
#pragma unroll
    for (int dt = 0; dt < 4; ++dt)
#pragma unroll
        for (int g = 0; g < 4; ++g) {
            int slot = ((dt << 2) | g) ^ (col & 7);     // bank swizzle (3-bit)
            u32 lo  = pack2(f2bf(o[dt][4 * g + 0] * inv), f2bf(o[dt][4 * g + 1] * inv));
            u32 hi2 = pack2(f2bf(o[dt][4 * g + 2] * inv), f2bf(o[dt][4 * g + 3] * inv));
            *(uint2*)(Tr + col * 128 + slot * 8 + 4 * hi) = make_uint2(lo, hi2);
        }
    size_t rowbase = (size_t)(b * T_ + qw0);
#pragma unroll
    for (int p = 0; p < 8; ++p) {
        int ql   = p * 4 + (lane >> 4);
        int slot = lane & 15;
        int dl   = (slot ^ (ql & 7)) * 8;
        u32x4_t v = *(const u32x4_t*)(Tr + ql * 128 + slot * 8);
        *(u32x4_t*)(attout + (rowbase + ql) * 2048 + h * HD_ + dl) = v;
    }
}

// ---------------------------------------------------------------------------
// launch
// ---------------------------------------------------------------------------
extern "C" void kernel_launch(void* const* d_in, const int* in_sizes, int n_in,
                              void* d_out, int out_size, void* d_ws, size_t ws_size,
                              hipStream_t stream) {
    const float* x    = (const float*)d_in[0];
    const float* Wq   = (const float*)d_in[1];
    const float* Wk   = (const float*)d_in[2];
    const float* Wv   = (const float*)d_in[3];
    const float* Wo   = (const float*)d_in[4];
    const float* qw   = (const float*)d_in[5];
    const float* kw   = (const float*)d_in[6];
    const float* sinT = (const float*)d_in[7];
    const float* cosT = (const float*)d_in[8];
    float* out = (float*)d_out;

    u16*  x_bf   = (u16*)d_ws;                                   // [4096][2048]
    u16*  wqkv_t = x_bf   + (size_t)M_ * D_;                     // [4096][2048]
    u16*  wo_t   = wqkv_t + (size_t)4096 * 2048;                 // [2048][2048]
    float* c_qkv = (float*)(wo_t + (size_t)2048 * 2048);         // [4096][4096]
    u16*  q_bf   = (u16*)(c_qkv + (size_t)M_ * NQKV_);           // [2][16][2048][128]
    u16*  k_bf   = q_bf + (size_t)B_ * H_  * T_ * HD_;           // [2][8][2048][128]
    u16*  v_bf   = k_bf + (size_t)B_ * KH_ * T_ * HD_;           // [2][8][2048][128]
    u16*  v_t    = v_bf + (size_t)B_ * KH_ * T_ * HD_;           // [2][8][128][2048]
    u16*  att_bf = v_t  + (size_t)B_ * KH_ * T_ * HD_;           // [4096][2048]

    cast_x_kernel<<<(M_ * D_) / 1024, 256, 0, stream>>>(x, x_bf);
    tcast_kernel<<<dim3(32, 32), 256, 0, stream>>>(Wq, wqkv_t, 2048);
    tcast_kernel<<<dim3(32, 16), 256, 0, stream>>>(Wk, wqkv_t + (size_t)2048 * 2048, 1024);
    tcast_kernel<<<dim3(32, 16), 256, 0, stream>>>(Wv, wqkv_t + (size_t)3072 * 2048, 1024);
    tcast_kernel<<<dim3(32, 32), 256, 0, stream>>>(Wo, wo_t, 2048);

    gemm8p_kernel<<<dim3(16, 16), 512, 0, stream>>>(x_bf, wqkv_t, c_qkv, 4096);
    normrope_kernel<<<(M_ * 32) / 4, 256, 0, stream>>>(c_qkv, qw, kw, sinT, cosT,
                                                       q_bf, k_bf, v_bf);
    vtrans_kernel<<<dim3(32, 2, 16), 256, 0, stream>>>(v_bf, v_t);
    attn_kernel<<<dim3(16, 16, 2), 256, 0, stream>>>(q_bf, k_bf, v_t, att_bf);
    gemm8p_kernel<<<dim3(16, 8), 512, 0, stream>>>(att_bf, wo_t, out, 2048);
}